// Round 2
// baseline (7502.540 us; speedup 1.0000x reference)
//
#include <hip/hip_runtime.h>

typedef __attribute__((ext_vector_type(4))) float f4;
typedef __attribute__((ext_vector_type(2))) float f2;
typedef __attribute__((ext_vector_type(8))) short frag8;
typedef unsigned long long u64;
typedef unsigned int u32;
typedef unsigned short u16;

#define ALPHA 0.3f

// ---- ws layout (bytes) ----
#define WHH_OFF   0ull                 // 3072*1024 bf16 = 6291456
#define WIH_OFF   6291456ull           // 3072*128 bf16  = 786432
#define HBUF_OFF  7077888ull           // 2 parities * 8 groups * 65536 = 1048576
#define FLG_OFF   8126464ull           // 8 groups * 64 u32 monotonic step flags
#define ST1_OFF   8159232ull           // 256*2 fp32 = 2048
#define ZERO_LEN  1083392ull           // hbuf + flags region + st1

__device__ __forceinline__ u16 f2bf(float f) {
  u32 u = __float_as_uint(f);
  u32 r = (u + 0x7FFFu + ((u >> 16) & 1u)) >> 16;
  return (u16)r;
}
__device__ __forceinline__ float bf2f(u16 h) {
  return __uint_as_float(((u32)h) << 16);
}
__device__ __forceinline__ float sigmf(float x) {
  float e = __expf(-fabsf(x));
  float s = 1.0f / (1.0f + e);
  return x >= 0.f ? s : 1.0f - s;
}
__device__ __forceinline__ float tanhf_(float x) {
  float e = __expf(-2.0f * fabsf(x));
  float t = (1.0f - e) / (1.0f + e);
  return x >= 0.f ? t : -t;
}
__device__ __forceinline__ frag8 pack_bf16(f4 a, f4 b) {
  union { u16 h[8]; frag8 f; } u;
  u.h[0] = f2bf(a[0]); u.h[1] = f2bf(a[1]); u.h[2] = f2bf(a[2]); u.h[3] = f2bf(a[3]);
  u.h[4] = f2bf(b[0]); u.h[5] = f2bf(b[1]); u.h[6] = f2bf(b[2]); u.h[7] = f2bf(b[3]);
  return u.f;
}

// fp32 -> bf16 weight conversion (W_hh then W_ih), exact-sized grid.
__global__ void prep_bf16(const float* __restrict__ whh_f32,
                          const float* __restrict__ wih_f32,
                          u16* __restrict__ whh, u16* __restrict__ wih) {
  int i = blockIdx.x * 256 + threadIdx.x;
  const int nhh = 3072 * 1024;
  if (i < nhh) whh[i] = f2bf(whh_f32[i]);
  else         wih[i - nhh] = f2bf(wih_f32[i - nhh]);
}

#define ACC_ZERO() do {                                                        \
  _Pragma("unroll") for (int b_ = 0; b_ < 2; ++b_) {                           \
    _Pragma("unroll") for (int r_ = 0; r_ < 3; ++r_) acc[b_][r_] = zz;         \
    accn[b_] = zz; }                                                           \
} while (0)

// 6 gi MFMAs (W_ih part): r,z into acc[.][0..1], n into accn.
#define IH_MFMA() do {                                                         \
  acc[0][0] = __builtin_amdgcn_mfma_f32_16x16x32_bf16(smf0, wihf[0], acc[0][0], 0, 0, 0); \
  acc[1][0] = __builtin_amdgcn_mfma_f32_16x16x32_bf16(smf1, wihf[0], acc[1][0], 0, 0, 0); \
  acc[0][1] = __builtin_amdgcn_mfma_f32_16x16x32_bf16(smf0, wihf[1], acc[0][1], 0, 0, 0); \
  acc[1][1] = __builtin_amdgcn_mfma_f32_16x16x32_bf16(smf1, wihf[1], acc[1][1], 0, 0, 0); \
  accn[0]   = __builtin_amdgcn_mfma_f32_16x16x32_bf16(smf0, wihf[2], accn[0], 0, 0, 0);   \
  accn[1]   = __builtin_amdgcn_mfma_f32_16x16x32_bf16(smf1, wihf[2], accn[1], 0, 0, 0);   \
} while (0)

// 12 hh MFMAs consuming af[2j], af[2j+1] (r,z,n_h rows only).
#define HH_CHUNK(j) do {                                                       \
  _Pragma("unroll") for (int kk_ = 0; kk_ < 2; ++kk_) {                        \
    const int kb_ = 2 * (j) + kk_;                                             \
    _Pragma("unroll") for (int r_ = 0; r_ < 3; ++r_) {                         \
      acc[0][r_] = __builtin_amdgcn_mfma_f32_16x16x32_bf16(af[kb_][0], whhf[kb_][r_], acc[0][r_], 0, 0, 0); \
      acc[1][r_] = __builtin_amdgcn_mfma_f32_16x16x32_bf16(af[kb_][1], whhf[kb_][r_], acc[1][r_], 0, 0, 0); } } \
} while (0)

// 4 dwordx4 agent-coherent loads; issue order = vmcnt order.
#define AF_LOAD(j) asm volatile(                                               \
  "global_load_dwordx4 %0, %4, off sc0 sc1\n\t"                                \
  "global_load_dwordx4 %1, %4, off offset:1024 sc0 sc1\n\t"                    \
  "global_load_dwordx4 %2, %4, off offset:2048 sc0 sc1\n\t"                    \
  "global_load_dwordx4 %3, %4, off offset:3072 sc0 sc1"                        \
  : "=&v"(af[2 * (j)][0]), "=&v"(af[2 * (j)][1]),                              \
    "=&v"(af[2 * (j) + 1][0]), "=&v"(af[2 * (j) + 1][1])                       \
  : "v"(pb + (j) * 4096))

// Persistent GRU recurrence. 512 WGs = 8 groups (batch slices of 32) x 64 WGs
// (16 H-cols each), 2 WGs/CU (co-resident WGs from different groups overlap
// each other's exchange stalls). hbuf layout identical to the 32-WG version.
__global__ __launch_bounds__(256, 2) void gru_kernel(
    const float* __restrict__ x,       // [256][1024][128]
    const float* __restrict__ b_ih,    // [3072]
    const float* __restrict__ b_hh,    // [3072]
    const u16* __restrict__ whh,       // [3072][1024] bf16
    const u16* __restrict__ wih,       // [3072][128] bf16
    u64* __restrict__ hbuf,            // [2][8][8192] u64 (64KB per (p,g))
    u32* __restrict__ flags,           // [8][64] monotonic step counters
    float* __restrict__ st1)           // [256][2]
{
  __shared__ f4 xbuf[2048];            // 32 KB: [4 waves][64 gr][8 b-quads] swizzled
  const int wg = blockIdx.x;
  const int g = wg >> 6, w = wg & 63;
  const int tid = threadIdx.x;
  const int v = tid >> 6;              // wave = K-slice of 256
  const int l = tid & 63;
  const int lm = l & 15, lq = l >> 4;

  // ---- load weight fragments into registers (persistent) ----
  // B-frag 16x16x32: n = lane&15 -> gate row, k = (lane>>4)*8 + j
  frag8 whhf[8][3];
  frag8 wihf[3];
#pragma unroll
  for (int rt = 0; rt < 3; ++rt) {
    int grow = rt * 1024 + w * 16 + lm;          // global gate row (r,z,n)
    wihf[rt] = *(const frag8*)(wih + grow * 128 + v * 32 + lq * 8);
#pragma unroll
    for (int kb = 0; kb < 8; ++kb)
      whhf[kb][rt] = *(const frag8*)(whh + grow * 1024 + v * 256 + kb * 32 + lq * 8);
  }

  // ---- update-phase constants: thread <-> (batch-pair bp, col uc) ----
  const int uc = tid & 15;
  const int bp = tid >> 4;             // 0..15 -> batches 2bp, 2bp+1
  const int qd = bp >> 1, half = bp & 1;
  const int colg = w * 16 + uc;
  const float bir = b_ih[colg],         bhr = b_hh[colg];
  const float biz = b_ih[1024 + colg],  bhz = b_hh[1024 + colg];
  const float bin_ = b_ih[2048 + colg], bhn = b_hh[2048 + colg];
  f2 hprev = {0.f, 0.f};

  // ---- EMA state in registers, A-fragment order ----
  // lane l of wave v holds sm[b = bh*16+lm][i = v*32 + lq*8 + j], bh=0,1
  const float* xb0 = x + (size_t)(g * 32 + lm) * 131072 + v * 32 + lq * 8;
  const float* xb1 = x + (size_t)(g * 32 + 16 + lm) * 131072 + v * 32 + lq * 8;

  u32* flagbase = flags + (g << 6);
  u32* fself = flagbase + w;
  const f4 zz = {0.f, 0.f, 0.f, 0.f};
  const float A1 = 1.0f - ALPHA;

  // ---- prologue: EMA(0) = x(0); pack; gi(0) MFMAs ----
  f4 e0a = *(const f4*)xb0, e0b = *(const f4*)(xb0 + 4);
  f4 e1a = *(const f4*)xb1, e1b = *(const f4*)(xb1 + 4);
  frag8 smf0 = pack_bf16(e0a, e0b), smf1 = pack_bf16(e1a, e1b);
  f4 acc[2][3], accn[2];
  ACC_ZERO();
  IH_MFMA();

#pragma unroll 1
  for (int t = 0; t < 1024; ++t) {
    const char* hrd = (const char*)hbuf + ((size_t)((t & 1) * 8 + g) << 16);
    u64* hwrite = hbuf + (size_t)(((t + 1) & 1) * 8 + g) * 8192;

    // ---- issue h_t fragment loads (16x dwordx4, LLC) ----
    frag8 af[8][2];
    const char* pb = hrd + (v << 14) + (l << 4);
    AF_LOAD(0); AF_LOAD(1); AF_LOAD(2); AF_LOAD(3);

    // ---- hh MFMAs in 4 chunks with counted vmcnt. Wave0 carries the prev
    //      flag store (oldest in queue): waits 12-4j work for all waves. ----
    asm volatile("s_waitcnt vmcnt(12)"); __builtin_amdgcn_sched_barrier(0);
    HH_CHUNK(0);
    asm volatile("s_waitcnt vmcnt(8)");  __builtin_amdgcn_sched_barrier(0);
    HH_CHUNK(1);
    asm volatile("s_waitcnt vmcnt(4)");  __builtin_amdgcn_sched_barrier(0);
    HH_CHUNK(2);
    asm volatile("s_waitcnt vmcnt(0)");  __builtin_amdgcn_sched_barrier(0);
    HH_CHUNK(3);

    // ---- write K-partials to LDS (transposed, XOR-swizzled, b128) ----
    // D-frag: batch = bh*16 + lq*4 + reg, gate-row-in-tile = lm
#pragma unroll
    for (int bh = 0; bh < 2; ++bh) {
      int swzw = (bh * 4 + lq) ^ (lm & 7);
#pragma unroll
      for (int rt = 0; rt < 3; ++rt)
        xbuf[(((v * 64) + rt * 16 + lm) << 3) | swzw] = acc[bh][rt];
      xbuf[(((v * 64) + 48 + lm) << 3) | swzw] = accn[bh];
    }

    // ---- issue x(t+1) loads (consumed post-arrive; latency hides under
    //      gates + staging; drained by the pre-sync(4) vmcnt(0)) ----
    int tn = (t < 1023) ? t + 1 : 1023;  // clamp: last-iter loads discarded
    const float* xp0 = xb0 + (size_t)tn * 128;
    const float* xp1 = xb1 + (size_t)tn * 128;
    f4 xa0n, xc0n, xa1n, xc1n;
    asm volatile(
      "global_load_dwordx4 %0, %4, off\n\t"
      "global_load_dwordx4 %1, %4, off offset:16\n\t"
      "global_load_dwordx4 %2, %5, off\n\t"
      "global_load_dwordx4 %3, %5, off offset:16"
      : "=&v"(xa0n), "=&v"(xc0n), "=&v"(xa1n), "=&v"(xc1n)
      : "v"(xp0), "v"(xp1));

    __syncthreads();   // (1) partials visible

    // ---- gate update: thread handles 2 batches (2bp..) x 1 col (uc) ----
    {
      const f2* xb2 = (const f2*)xbuf;
      const int swz = qd ^ (uc & 7);
      f2 sr = {0.f, 0.f}, sz = {0.f, 0.f}, gnh = {0.f, 0.f}, gnx = {0.f, 0.f};
#pragma unroll
      for (int vv = 0; vv < 4; ++vv) {
        int b0i = vv * 64;
        sr  += xb2[(((b0i + uc) << 3) | swz) * 2 + half];
        sz  += xb2[(((b0i + 16 + uc) << 3) | swz) * 2 + half];
        gnh += xb2[(((b0i + 32 + uc) << 3) | swz) * 2 + half];
        gnx += xb2[(((b0i + 48 + uc) << 3) | swz) * 2 + half];
      }
      f2 h2v;
#pragma unroll
      for (int i = 0; i < 2; ++i) {
        float rr = sigmf(sr[i] + bir + bhr);
        float zg = sigmf(sz[i] + biz + bhz);
        float nn = tanhf_(gnx[i] + bin_ + rr * (gnh[i] + bhn));
        h2v[i] = (1.0f - zg) * nn + zg * hprev[i];
      }
      hprev = h2v;
      __syncthreads();   // (2) xbuf reads done, safe to reuse as staging

      // ---- stage h(bf16) in LDS in consumer order ----
      // sbuf u16 idx = ((bh*2 + (uc>>3))*128) + (b&15)*8 + (uc&7)
      u16* sbuf = (u16*)&xbuf[0];
#pragma unroll
      for (int i = 0; i < 2; ++i) {
        int b = 2 * bp + i;
        sbuf[((((b >> 4) << 1) | (uc >> 3)) << 7) + ((b & 15) << 3) + (uc & 7)] =
            f2bf(h2v[i]);
      }
    }
    __syncthreads();   // (3)

    // ---- store h to hwrite: 128 u64, A-fragment-ordered ----
    if (tid < 128) {
      const u16* sbuf = (const u16*)&xbuf[0];
      u64 pk = ((const u64*)sbuf)[tid];
      int bh_ = tid >> 6, q_ = (tid >> 5) & 1, lmv = (tid >> 1) & 15, sub = tid & 1;
      int off = (((w >> 1) * 2 + bh_) * 64 + ((w & 1) * 2 + q_) * 16 + lmv) * 2 + sub;
      __hip_atomic_store(hwrite + off, pk, __ATOMIC_RELAXED, __HIP_MEMORY_SCOPE_AGENT);
    }
    asm volatile("s_waitcnt vmcnt(0)" ::: "memory");  // h stores + x loads drained
    __builtin_amdgcn_sched_barrier(0);
    __syncthreads();   // (4)

    if (t < 1023) {
      // ---- arrive: fire-and-forget flag store ----
      if (tid == 0)
        asm volatile("global_store_dword %0, %1, off sc0 sc1"
                     :: "v"(fself), "v"((u32)(t + 1)) : "memory");
      __builtin_amdgcn_sched_barrier(0);

      // ---- overlapped with arrival: EMA(t+1), pack, gi MFMAs ----
      e0a = A1 * xa0n + ALPHA * e0a; e0b = A1 * xc0n + ALPHA * e0b;
      e1a = A1 * xa1n + ALPHA * e1a; e1b = A1 * xc1n + ALPHA * e1b;
      if (t == 1022 && w == 0 && v == 0 && lq == 0) {
        // st_1 = EMA at t=1023; columns 1,2 for denorm
        st1[(g * 32 + lm) * 2 + 0] = e0a[1];
        st1[(g * 32 + lm) * 2 + 1] = e0a[2];
        st1[(g * 32 + 16 + lm) * 2 + 0] = e1a[1];
        st1[(g * 32 + 16 + lm) * 2 + 1] = e1a[2];
      }
      smf0 = pack_bf16(e0a, e0b); smf1 = pack_bf16(e1a, e1b);
      ACC_ZERO();
      IH_MFMA();

      // ---- wait: 64-lane coalesced poll of all 64 group flags ----
      if (tid < 64) {
        const u32* fp = flagbase + tid;
        while (1) {
          u32 fv;
          asm volatile("global_load_dword %0, %1, off sc0 sc1\n\t"
                       "s_waitcnt vmcnt(0)"
                       : "=v"(fv) : "v"(fp) : "memory");
          if (__ballot(fv > (u32)t) == ~0ull) break;
          __builtin_amdgcn_s_sleep(1);
        }
      }
      __syncthreads();   // (5) release whole WG into next step
    }
  }
}

// out[b][o] = (h_T[b] . W_fc[o] + b_fc[o] - a*st1[b][o]) / (1-a)
__global__ void fc_kernel(const u16* __restrict__ hbuf_bf,  // parity-0 region
                          const float* __restrict__ wfc,    // [2][1024]
                          const float* __restrict__ bfc,    // [2]
                          const float* __restrict__ st1,    // [256][2]
                          float* __restrict__ out)          // [256][2]
{
  int b = blockIdx.x, t = threadIdx.x;
  int g = b >> 5, bl = b & 31, bh = bl >> 4;
  int k0 = t * 4, kb = k0 >> 5, ko = k0 & 31;
  int lane = (bl & 15) + 16 * (ko >> 3);
  const u16* hp = hbuf_bf + (size_t)g * 32768 + ((kb * 2 + bh) * 64 + lane) * 8 + (ko & 7);
  float h0 = bf2f(hp[0]), h1 = bf2f(hp[1]), h2 = bf2f(hp[2]), h3 = bf2f(hp[3]);
  float s0 = h0 * wfc[k0] + h1 * wfc[k0 + 1] + h2 * wfc[k0 + 2] + h3 * wfc[k0 + 3];
  float s1 = h0 * wfc[1024 + k0] + h1 * wfc[1024 + k0 + 1] +
             h2 * wfc[1024 + k0 + 2] + h3 * wfc[1024 + k0 + 3];
#pragma unroll
  for (int off = 32; off > 0; off >>= 1) {
    s0 += __shfl_down(s0, off);
    s1 += __shfl_down(s1, off);
  }
  __shared__ float red[8];
  if ((t & 63) == 0) { red[(t >> 6) * 2] = s0; red[(t >> 6) * 2 + 1] = s1; }
  __syncthreads();
  if (t == 0) {
    float a0 = red[0] + red[2] + red[4] + red[6] + bfc[0];
    float a1 = red[1] + red[3] + red[5] + red[7] + bfc[1];
    float inv = 1.0f / (1.0f - ALPHA);
    out[b * 2 + 0] = (a0 - ALPHA * st1[b * 2 + 0]) * inv;
    out[b * 2 + 1] = (a1 - ALPHA * st1[b * 2 + 1]) * inv;
  }
}

extern "C" void kernel_launch(void* const* d_in, const int* in_sizes, int n_in,
                              void* d_out, int out_size, void* d_ws, size_t ws_size,
                              hipStream_t stream) {
  const float* x   = (const float*)d_in[0];
  const float* Wih = (const float*)d_in[1];
  const float* Whh = (const float*)d_in[2];
  const float* bih = (const float*)d_in[3];
  const float* bhh = (const float*)d_in[4];
  const float* Wfc = (const float*)d_in[5];
  const float* bfc = (const float*)d_in[6];
  char* ws = (char*)d_ws;
  u16* whh_bf = (u16*)(ws + WHH_OFF);
  u16* wih_bf = (u16*)(ws + WIH_OFF);
  u64* hbuf   = (u64*)(ws + HBUF_OFF);
  u32* flg    = (u32*)(ws + FLG_OFF);
  float* st1  = (float*)(ws + ST1_OFF);

  hipMemsetAsync(ws + HBUF_OFF, 0, ZERO_LEN, stream);
  prep_bf16<<<13824, 256, 0, stream>>>(Whh, Wih, whh_bf, wih_bf);
  gru_kernel<<<512, 256, 0, stream>>>(x, bih, bhh, whh_bf, wih_bf, hbuf, flg, st1);
  fc_kernel<<<256, 256, 0, stream>>>((const u16*)(ws + HBUF_OFF), Wfc, bfc, st1,
                                     (float*)d_out);
}

// Round 8
// 4026.136 us; speedup vs baseline: 1.8635x; 1.8635x over previous
//
#include <hip/hip_runtime.h>

typedef __attribute__((ext_vector_type(4))) float f4;
typedef __attribute__((ext_vector_type(8))) short frag8;
typedef unsigned long long u64;
typedef unsigned int u32;
typedef unsigned short u16;

#define ALPHA 0.3f

// ---- ws layout (bytes) ----
#define WHH_OFF   0ull                 // 3072*1024 bf16 = 6291456
#define WIH_OFF   6291456ull           // 3072*128 bf16  = 786432
#define HBUF_OFF  7077888ull           // 2 parities * 8 groups * 65536 = 1048576
#define FLG_OFF   8126464ull           // 8 groups * 32 u32 monotonic step flags
#define ST1_OFF   8159232ull           // 256*2 fp32 = 2048
#define XCC_OFF   8161280ull           // 256 u32 per-WG xcc-id (+1)
#define ZERO_LEN  1084416ull           // hbuf + flags + st1 + xcc

__device__ __forceinline__ u16 f2bf(float f) {
  u32 u = __float_as_uint(f);
  u32 r = (u + 0x7FFFu + ((u >> 16) & 1u)) >> 16;
  return (u16)r;
}
__device__ __forceinline__ float bf2f(u16 h) {
  return __uint_as_float(((u32)h) << 16);
}
__device__ __forceinline__ float sigmf(float x) {
  float e = __expf(-fabsf(x));
  float s = 1.0f / (1.0f + e);
  return x >= 0.f ? s : 1.0f - s;
}
__device__ __forceinline__ float tanhf_(float x) {
  float e = __expf(-2.0f * fabsf(x));
  float t = (1.0f - e) / (1.0f + e);
  return x >= 0.f ? t : -t;
}
__device__ __forceinline__ frag8 pack_bf16(f4 a, f4 b) {
  union { u16 h[8]; frag8 f; } u;
  u.h[0] = f2bf(a[0]); u.h[1] = f2bf(a[1]); u.h[2] = f2bf(a[2]); u.h[3] = f2bf(a[3]);
  u.h[4] = f2bf(b[0]); u.h[5] = f2bf(b[1]); u.h[6] = f2bf(b[2]); u.h[7] = f2bf(b[3]);
  return u.f;
}

// fp32 -> bf16 weight conversion (W_hh then W_ih), exact-sized grid.
__global__ void prep_bf16(const float* __restrict__ whh_f32,
                          const float* __restrict__ wih_f32,
                          u16* __restrict__ whh, u16* __restrict__ wih) {
  int i = blockIdx.x * 256 + threadIdx.x;
  const int nhh = 3072 * 1024;
  if (i < nhh) whh[i] = f2bf(whh_f32[i]);
  else         wih[i - nhh] = f2bf(wih_f32[i - nhh]);
}

#define ACC_ZERO() do {                                                        \
  _Pragma("unroll") for (int bh_ = 0; bh_ < 2; ++bh_) {                        \
    _Pragma("unroll") for (int rt_ = 0; rt_ < 6; ++rt_) acc[bh_][rt_] = zz;    \
    accn[bh_][0] = zz; accn[bh_][1] = zz; }                                    \
} while (0)

#define IH_MFMA() do {                                                         \
  _Pragma("unroll") for (int rt_ = 0; rt_ < 4; ++rt_) {                        \
    acc[0][rt_] = __builtin_amdgcn_mfma_f32_16x16x32_bf16(smf0, wihf[rt_], acc[0][rt_], 0, 0, 0); \
    acc[1][rt_] = __builtin_amdgcn_mfma_f32_16x16x32_bf16(smf1, wihf[rt_], acc[1][rt_], 0, 0, 0); } \
  _Pragma("unroll") for (int nt_ = 0; nt_ < 2; ++nt_) {                        \
    accn[0][nt_] = __builtin_amdgcn_mfma_f32_16x16x32_bf16(smf0, wihf[4 + nt_], accn[0][nt_], 0, 0, 0); \
    accn[1][nt_] = __builtin_amdgcn_mfma_f32_16x16x32_bf16(smf1, wihf[4 + nt_], accn[1][nt_], 0, 0, 0); } \
} while (0)

// 24 hh MFMAs consuming af[2j], af[2j+1].
#define HH_CHUNK(j) do {                                                       \
  _Pragma("unroll") for (int kk_ = 0; kk_ < 2; ++kk_) {                        \
    const int kb_ = 2 * (j) + kk_;                                             \
    _Pragma("unroll") for (int rt_ = 0; rt_ < 6; ++rt_) {                      \
      acc[0][rt_] = __builtin_amdgcn_mfma_f32_16x16x32_bf16(af[kb_][0], whhf[kb_][rt_], acc[0][rt_], 0, 0, 0); \
      acc[1][rt_] = __builtin_amdgcn_mfma_f32_16x16x32_bf16(af[kb_][1], whhf[kb_][rt_], acc[1][rt_], 0, 0, 0); } } \
} while (0)

// 4 dwordx4 coherent loads; issue order = vmcnt order. SC = cache bits:
// "sc0" (XCD-local, L2 coherence point) or "sc0 sc1" (device, LLC).
#define AF_LOAD(j, SC) asm volatile(                                           \
  "global_load_dwordx4 %0, %4, off " SC "\n\t"                                 \
  "global_load_dwordx4 %1, %4, off offset:1024 " SC "\n\t"                     \
  "global_load_dwordx4 %2, %4, off offset:2048 " SC "\n\t"                     \
  "global_load_dwordx4 %3, %4, off offset:3072 " SC                            \
  : "=&v"(af[2 * (j)][0]), "=&v"(af[2 * (j)][1]),                              \
    "=&v"(af[2 * (j) + 1][0]), "=&v"(af[2 * (j) + 1][1])                       \
  : "v"(pb + (j) * 4096))

#define H_STORE(SC) asm volatile("global_store_dwordx2 %0, %1, off " SC        \
  :: "v"(hwrite + off), "v"(pk) : "memory")

// Persistent GRU recurrence. 256 WGs = 8 groups (batch slices of 32) x 32 WGs
// (32 H-cols each). Group g = wg&7: under round-robin dispatch the 32 WGs of a
// group share one XCD -> h exchange (af loads, h stores) runs sc0-only through
// that XCD's L2. Step-barrier flags stay DEVICE scope (sc0 sc1) -- identical
// to the proven R1 structure. Co-location verified at runtime with a
// barrier-style check (same poll shape as the step barrier; no leader, no
// verdict word): entries are write-once, so all members compute the same
// verdict from the same stable data. Fallback verdict -> R1 behavior.
__global__ __launch_bounds__(256, 1) void gru_kernel(
    const float* __restrict__ x,       // [256][1024][128]
    const float* __restrict__ b_ih,    // [3072]
    const float* __restrict__ b_hh,    // [3072]
    const u16* __restrict__ whh,       // [3072][1024] bf16
    const u16* __restrict__ wih,       // [3072][128] bf16
    u64* __restrict__ hbuf,            // [2][8][8192] u64 (64KB per (p,g))
    u32* __restrict__ flags,           // [8][32] monotonic step counters
    u32* __restrict__ xccarr,          // [256] xcc-id + 1
    float* __restrict__ st1)           // [256][2]
{
  __shared__ f4 xbuf[4096];            // 64 KB: [4 waves][128 gr][8 b-quads] swizzled
  const int wg = blockIdx.x;
  const int g = wg & 7, w = wg >> 3;   // group spans one XCD under round-robin
  const int tid = threadIdx.x;
  const int v = tid >> 6;              // wave = K-slice of 256
  const int l = tid & 63;
  const int lm = l & 15, lq = l >> 4;

  // ---- load weight fragments into registers (persistent) ----
  frag8 whhf[8][6];
  frag8 wihf[6];
#pragma unroll
  for (int rt = 0; rt < 6; ++rt) {
    int grow = (rt >> 1) * 1024 + w * 32 + (rt & 1) * 16 + lm;  // global gate row
    wihf[rt] = *(const frag8*)(wih + grow * 128 + v * 32 + lq * 8);
#pragma unroll
    for (int kb = 0; kb < 8; ++kb)
      whhf[kb][rt] = *(const frag8*)(whh + grow * 1024 + v * 256 + kb * 32 + lq * 8);
  }

  // ---- update-phase constants ----
  const int uc = tid & 31;
  const int ub0 = (tid >> 5) << 2;
  const int colg = w * 32 + uc;
  const float bir = b_ih[colg],         bhr = b_hh[colg];
  const float biz = b_ih[1024 + colg],  bhz = b_hh[1024 + colg];
  const float bin_ = b_ih[2048 + colg], bhn = b_hh[2048 + colg];
  f4 hprev = {0.f, 0.f, 0.f, 0.f};

  const float* xb0 = x + (size_t)(g * 32 + lm) * 131072 + v * 32 + lq * 8;
  const float* xb1 = x + (size_t)(g * 32 + 16 + lm) * 131072 + v * 32 + lq * 8;

  u32* flagbase = flags + (g << 5);
  u32* fself = flagbase + w;
  const f4 zz = {0.f, 0.f, 0.f, 0.f};
  const float A1 = 1.0f - ALPHA;

  // ---- one-time XCD co-location check: barrier-style, no leader ----
  // Publish xcc+1; wave0 polls the 32 group entries (write-once data) with the
  // exact poll shape of the step barrier; verdict computed locally, uniform
  // across the group because all read the same stable values.
  u32 myxcc;
  asm volatile("s_getreg_b32 %0, hwreg(HW_REG_XCC_ID)" : "=s"(myxcc));
  myxcc &= 15u;
  if (tid == 0) {
    u32 pub = myxcc + 1u;
    asm volatile("global_store_dword %0, %1, off sc0 sc1"
                 :: "v"(xccarr + wg), "v"(pub) : "memory");
  }
  if (tid < 64) {
    const u32* xp = xccarr + ((((tid & 31) << 3) | g));  // member (tid&31) of group g
    u32 vv;
    while (1) {
      asm volatile("global_load_dword %0, %1, off sc0 sc1\n\ts_waitcnt vmcnt(0)"
                   : "=v"(vv) : "v"(xp) : "memory");
      if (__ballot(vv != 0u) == ~0ull) break;
      __builtin_amdgcn_s_sleep(1);
    }
    u32 same = (__ballot(vv == myxcc + 1u) == ~0ull) ? 1u : 0u;
    if (tid == 0) *(volatile u32*)&xbuf[0] = same;
  }
  __syncthreads();
  const bool locl = (*(volatile u32*)&xbuf[0]) != 0u;
  __syncthreads();   // xbuf[0] consumed before first loop LDS write

  // ---- prologue: EMA(0) = x(0); pack; gi(0) MFMAs ----
  f4 e0a = *(const f4*)xb0, e0b = *(const f4*)(xb0 + 4);
  f4 e1a = *(const f4*)xb1, e1b = *(const f4*)(xb1 + 4);
  frag8 smf0 = pack_bf16(e0a, e0b), smf1 = pack_bf16(e1a, e1b);
  f4 acc[2][6], accn[2][2];
  ACC_ZERO();
  IH_MFMA();

#pragma unroll 1
  for (int t = 0; t < 1024; ++t) {
    const char* hrd = (const char*)hbuf + ((size_t)((t & 1) * 8 + g) << 16);
    u64* hwrite = hbuf + (size_t)(((t + 1) & 1) * 8 + g) * 8192;

    // ---- issue h_t fragment loads (16x dwordx4; XCD L2 if local, LLC else) ----
    frag8 af[8][2];
    const char* pb = hrd + (v << 14) + (l << 4);
    if (locl) { AF_LOAD(0, "sc0"); AF_LOAD(1, "sc0"); AF_LOAD(2, "sc0"); AF_LOAD(3, "sc0"); }
    else      { AF_LOAD(0, "sc0 sc1"); AF_LOAD(1, "sc0 sc1"); AF_LOAD(2, "sc0 sc1"); AF_LOAD(3, "sc0 sc1"); }

    // ---- issue x(t+1) prefetch (plain cached loads; consumed post-arrive) ----
    int tn = (t < 1023) ? t + 1 : 1023;  // clamp: last-iter loads are discarded
    const float* xp0 = xb0 + (size_t)tn * 128;
    const float* xp1 = xb1 + (size_t)tn * 128;
    f4 xa0n, xc0n, xa1n, xc1n;
    asm volatile(
      "global_load_dwordx4 %0, %4, off\n\t"
      "global_load_dwordx4 %1, %4, off offset:16\n\t"
      "global_load_dwordx4 %2, %5, off\n\t"
      "global_load_dwordx4 %3, %5, off offset:16"
      : "=&v"(xa0n), "=&v"(xc0n), "=&v"(xa1n), "=&v"(xc1n)
      : "v"(xp0), "v"(xp1));

    // ---- hh MFMAs in 4 chunks with counted vmcnt (20 outstanding:
    //      16 af + 4 x; chunk j needs af loads 0..4j+3 done) ----
    asm volatile("s_waitcnt vmcnt(16)"); __builtin_amdgcn_sched_barrier(0);
    HH_CHUNK(0);
    asm volatile("s_waitcnt vmcnt(12)"); __builtin_amdgcn_sched_barrier(0);
    HH_CHUNK(1);
    asm volatile("s_waitcnt vmcnt(8)");  __builtin_amdgcn_sched_barrier(0);
    HH_CHUNK(2);
    asm volatile("s_waitcnt vmcnt(4)");  __builtin_amdgcn_sched_barrier(0);
    HH_CHUNK(3);

    // ---- write K-partials to LDS (transposed, XOR-swizzled, b128) ----
#pragma unroll
    for (int bh = 0; bh < 2; ++bh) {
      int b8 = bh * 4 + lq;
#pragma unroll
      for (int rt = 0; rt < 6; ++rt) {
        int gr = rt * 16 + lm;
        xbuf[((v * 128 + gr) << 3) | (b8 ^ (gr & 7))] = acc[bh][rt];
      }
#pragma unroll
      for (int nt = 0; nt < 2; ++nt) {
        int gr = 96 + nt * 16 + lm;
        xbuf[((v * 128 + gr) << 3) | (b8 ^ (gr & 7))] = accn[bh][nt];
      }
    }
    __syncthreads();   // (1) partials visible

    // ---- gate update: thread handles 4 batches (ub0..) x 1 col (uc) ----
    int swz = (ub0 >> 2) ^ (uc & 7);
    f4 sr = zz, sz4 = zz, gn4 = zz, gin4 = zz;
#pragma unroll
    for (int vv = 0; vv < 4; ++vv) {
      sr   += xbuf[((vv * 128 + uc) << 3) | swz];
      sz4  += xbuf[((vv * 128 + 32 + uc) << 3) | swz];
      gn4  += xbuf[((vv * 128 + 64 + uc) << 3) | swz];
      gin4 += xbuf[((vv * 128 + 96 + uc) << 3) | swz];
    }
    f4 h4;
#pragma unroll
    for (int i = 0; i < 4; ++i) {
      float rr = sigmf(sr[i] + bir + bhr);
      float zg = sigmf(sz4[i] + biz + bhz);
      float nn = tanhf_(gin4[i] + bin_ + rr * (gn4[i] + bhn));
      h4[i] = (1.0f - zg) * nn + zg * hprev[i];
    }
    hprev = h4;
    __syncthreads();   // (2) xbuf reads done, safe to reuse as staging

    // ---- stage h(bf16) in LDS, repack to 8B, store to hwrite ----
    u16* sbuf = (u16*)&xbuf[0];        // [32 b][stride 40]
#pragma unroll
    for (int i = 0; i < 4; ++i) sbuf[(ub0 + i) * 40 + uc] = f2bf(h4[i]);
    __syncthreads();   // (3)
    {
      int b = tid >> 3, c0 = (tid & 7) << 2;
      u64 pk = *(const u64*)(sbuf + b * 40 + c0);
      int off = ((w * 2 + (b >> 4)) * 64 + (b & 15) + 16 * (c0 >> 3)) * 2 + ((c0 & 7) >> 2);
      if (locl) H_STORE("sc0");
      else      H_STORE("sc0 sc1");
    }
    asm volatile("s_waitcnt vmcnt(0)" ::: "memory");  // h stores at coherence point
    __syncthreads();   // (4) whole WG drained before signaling

    if (t < 1023) {
      // ---- arrive: fire-and-forget flag store (DEVICE scope, as proven) ----
      if (tid == 0)
        asm volatile("global_store_dword %0, %1, off sc0 sc1"
                     :: "v"(fself), "v"((u32)(t + 1)) : "memory");

      // x prefetch already retired; wave0 skips its in-flight flag store
      // (vmcnt retires in order: flag is the only outstanding op).
      if (tid < 64) asm volatile("s_waitcnt vmcnt(1)" ::: "memory");
      else          asm volatile("s_waitcnt vmcnt(0)" ::: "memory");
      __builtin_amdgcn_sched_barrier(0);

      // ---- overlapped with other WGs' arrival: EMA(t+1), pack, gi MFMAs ----
      e0a = A1 * xa0n + ALPHA * e0a; e0b = A1 * xc0n + ALPHA * e0b;
      e1a = A1 * xa1n + ALPHA * e1a; e1b = A1 * xc1n + ALPHA * e1b;
      if (t == 1022 && w == 0 && v == 0 && lq == 0) {
        // st_1 = EMA at t=1023; columns 1,2 for denorm
        st1[(g * 32 + lm) * 2 + 0] = e0a[1];
        st1[(g * 32 + lm) * 2 + 1] = e0a[2];
        st1[(g * 32 + 16 + lm) * 2 + 0] = e1a[1];
        st1[(g * 32 + 16 + lm) * 2 + 1] = e1a[2];
      }
      smf0 = pack_bf16(e0a, e0b); smf1 = pack_bf16(e1a, e1b);
      ACC_ZERO();
      IH_MFMA();

      // ---- wait: 64-lane coalesced poll of all 32 group flags (DEVICE) ----
      if (tid < 64) {
        const u32* fp = flagbase + (tid & 31);
        u32 fv;
        while (1) {
          asm volatile("global_load_dword %0, %1, off sc0 sc1\n\t"
                       "s_waitcnt vmcnt(0)"
                       : "=v"(fv) : "v"(fp) : "memory");
          if (__ballot(fv > (u32)t) == ~0ull) break;
          __builtin_amdgcn_s_sleep(1);
        }
      }
      __syncthreads();   // (5) release whole WG into next step
    }
  }
}

// out[b][o] = (h_T[b] . W_fc[o] + b_fc[o] - a*st1[b][o]) / (1-a)
__global__ void fc_kernel(const u16* __restrict__ hbuf_bf,  // parity-0 region
                          const float* __restrict__ wfc,    // [2][1024]
                          const float* __restrict__ bfc,    // [2]
                          const float* __restrict__ st1,    // [256][2]
                          float* __restrict__ out)          // [256][2]
{
  int b = blockIdx.x, t = threadIdx.x;
  int g = b >> 5, bl = b & 31, bh = bl >> 4;
  int k0 = t * 4, kb = k0 >> 5, ko = k0 & 31;
  int lane = (bl & 15) + 16 * (ko >> 3);
  const u16* hp = hbuf_bf + (size_t)g * 32768 + ((kb * 2 + bh) * 64 + lane) * 8 + (ko & 7);
  float h0 = bf2f(hp[0]), h1 = bf2f(hp[1]), h2 = bf2f(hp[2]), h3 = bf2f(hp[3]);
  float s0 = h0 * wfc[k0] + h1 * wfc[k0 + 1] + h2 * wfc[k0 + 2] + h3 * wfc[k0 + 3];
  float s1 = h0 * wfc[1024 + k0] + h1 * wfc[1024 + k0 + 1] +
             h2 * wfc[1024 + k0 + 2] + h3 * wfc[1024 + k0 + 3];
#pragma unroll
  for (int off = 32; off > 0; off >>= 1) {
    s0 += __shfl_down(s0, off);
    s1 += __shfl_down(s1, off);
  }
  __shared__ float red[8];
  if ((t & 63) == 0) { red[(t >> 6) * 2] = s0; red[(t >> 6) * 2 + 1] = s1; }
  __syncthreads();
  if (t == 0) {
    float a0 = red[0] + red[2] + red[4] + red[6] + bfc[0];
    float a1 = red[1] + red[3] + red[5] + red[7] + bfc[1];
    float inv = 1.0f / (1.0f - ALPHA);
    out[b * 2 + 0] = (a0 - ALPHA * st1[b * 2 + 0]) * inv;
    out[b * 2 + 1] = (a1 - ALPHA * st1[b * 2 + 1]) * inv;
  }
}

extern "C" void kernel_launch(void* const* d_in, const int* in_sizes, int n_in,
                              void* d_out, int out_size, void* d_ws, size_t ws_size,
                              hipStream_t stream) {
  const float* x   = (const float*)d_in[0];
  const float* Wih = (const float*)d_in[1];
  const float* Whh = (const float*)d_in[2];
  const float* bih = (const float*)d_in[3];
  const float* bhh = (const float*)d_in[4];
  const float* Wfc = (const float*)d_in[5];
  const float* bfc = (const float*)d_in[6];
  char* ws = (char*)d_ws;
  u16* whh_bf = (u16*)(ws + WHH_OFF);
  u16* wih_bf = (u16*)(ws + WIH_OFF);
  u64* hbuf   = (u64*)(ws + HBUF_OFF);
  u32* flg    = (u32*)(ws + FLG_OFF);
  u32* xcc    = (u32*)(ws + XCC_OFF);
  float* st1  = (float*)(ws + ST1_OFF);

  hipMemsetAsync(ws + HBUF_OFF, 0, ZERO_LEN, stream);
  prep_bf16<<<13824, 256, 0, stream>>>(Whh, Wih, whh_bf, wih_bf);
  gru_kernel<<<256, 256, 0, stream>>>(x, bih, bhh, whh_bf, wih_bf, hbuf, flg, xcc, st1);
  fc_kernel<<<256, 256, 0, stream>>>((const u16*)(ws + HBUF_OFF), Wfc, bfc, st1,
                                     (float*)d_out);
}